// Round 8
// baseline (350.820 us; speedup 1.0000x reference)
//
#include <hip/hip_runtime.h>
#include <cstdint>

// Problem constants
#define NROWS   131072
#define NUNITS  256
#define KTOT    512          // INPUT_DIM + UNITS
#define BM      256          // rows per block (m201 geometry)
#define THREADS 512

typedef float f32x4  __attribute__((ext_vector_type(4)));
typedef short bf16x8 __attribute__((ext_vector_type(8)));

__device__ __forceinline__ short f2bf(float x) {
    unsigned u = __float_as_uint(x);
    u += 0x7FFFu + ((u >> 16) & 1u);   // round-to-nearest-even
    return (short)(u >> 16);
}

// Fused prepass: blocks [0,32768) convert x|h -> Aws bf16 [row][512];
// blocks [32768,34816) convert W fp32 [512][1024] -> Wws [16][1024][32] bf16
// (per-K32-step, column-major, 32 contiguous k per col = B-frag order).
__global__ void convert_kernel(const float* __restrict__ x, const float* __restrict__ h,
                               const float* __restrict__ W,
                               short* __restrict__ Aws, short* __restrict__ Wws) {
    int b = blockIdx.x;
    if (b < 32768) {
        int i = b * 256 + threadIdx.x;       // 0 .. 8388607
        int row = i >> 6;
        int c   = (i & 63) * 4;
        float4 xv = *(const float4*)(x + (size_t)row * 256 + c);
        float4 hv = *(const float4*)(h + (size_t)row * 256 + c);
        short xs[4] = {f2bf(xv.x), f2bf(xv.y), f2bf(xv.z), f2bf(xv.w)};
        short hs[4] = {f2bf(hv.x), f2bf(hv.y), f2bf(hv.z), f2bf(hv.w)};
        *(uint2*)(Aws + (size_t)row * 512 + c)       = *(uint2*)xs;
        *(uint2*)(Aws + (size_t)row * 512 + 256 + c) = *(uint2*)hs;
    } else {
        int i = (b - 32768) * 256 + threadIdx.x;   // 0 .. 524287
        int k = i >> 10;
        int c = i & 1023;
        Wws[((size_t)(k >> 5) << 15) + ((size_t)c << 5) + (k & 31)] = f2bf(W[i]);
    }
}

// Main (m201 256^2 geometry): grid 2048 = 512 row-tiles x 4 u-tiles (XCD-swz).
// Block: 256 rows x 64 u-cols x 4 gates (256 output cols). 8 waves = 2 row-
// halves x 4 col-quarters; wave tile 128x64, acc[8][4] (all gates lane-local).
// K-loop: 8 phases of BK=64 (stored as 2x BK=32 sub-tiles to keep the
// R7-proven conflict-free LDS layout: 64B row stride + (row>>1)&3 granule XOR,
// pre-swizzled on the DMA SOURCE, LDS dest linear -- rule #21).
// Per phase/wave: 64 MFMA vs 24 ds_read_b128 + 8 global_load_lds; double-
// buffered 2x64KB LDS; DMA(p+1) issued post-barrier -> ~1 full phase in
// flight; single counted wait per phase; setprio around MFMA clusters (T5).
__global__ void __launch_bounds__(THREADS, 2)
lstm_main_kernel(const float* __restrict__ c_prev, const float* __restrict__ bias,
                 const float* __restrict__ pi, const float* __restrict__ pf,
                 const float* __restrict__ po, const short* __restrict__ Aws,
                 const short* __restrict__ Wws, float* __restrict__ out) {
    __shared__ short lds[2][32768];   // per buf: A [2][8192], B at 16384 + [2][8192]

    // XCD-aware bijective swizzle (2048 % 8 == 0): the 4 u-tiles of one
    // row-panel land on the same XCD adjacent in time -> A panel L2-reused.
    const int bid = blockIdx.x;
    const int swz = (bid & 7) * 256 + (bid >> 3);
    const int ut  = swz & 3;
    const int rt  = swz >> 2;
    const int row0 = rt * BM;

    const int t    = threadIdx.x;
    const int lane = t & 63;
    const int w    = t >> 6;
    const int lr   = lane & 15;
    const int hi   = lane >> 4;          // k-granule 0..3
    const int rh   = w >> 2;             // row half 0..1 (128 rows each)
    const int q    = w & 3;              // col quarter 0..3 (16 u each)

    // ---- per-thread DMA source bases (granule-swizzled with (row>>1)&3) ----
    const short* srcA[2];
    const short* srcB[2];
    #pragma unroll
    for (int rep = 0; rep < 2; ++rep) {
        const int G    = rep * 512 + t;          // granule id 0..1023
        const int arow = G >> 2, ag = G & 3;     // A: row 0..255, granule 0..3
        srcA[rep] = Aws + (size_t)(row0 + arow) * 512 + ((ag ^ ((arow >> 1) & 3)) * 8);
        const int cp = G >> 2, bg = G & 3;       // B: LDS col 0..255
        const int gate = cp >> 6, u64 = cp & 63;
        srcB[rep] = Wws + (size_t)(gate * 256 + ut * 64 + u64) * 32
                        + ((bg ^ ((cp >> 1) & 3)) * 8);
    }

    // ---- fragment read offsets (shorts, within one 32K-short buffer) ----
    const int sw    = (hi ^ ((lr >> 1) & 3)) * 8;
    const int abase = (rh * 128 + lr) * 32 + sw;          // + m*512 + kk*8192
    const int bbase = 16384 + (q * 16 + lr) * 32 + sw;    // + g*2048 + kk*8192

    f32x4 acc[8][4];
    #pragma unroll
    for (int m = 0; m < 8; ++m)
        #pragma unroll
        for (int g = 0; g < 4; ++g)
            acc[m][g] = (f32x4){0.f, 0.f, 0.f, 0.f};

    auto dma = [&](int kt, int buf) {
        short* base = &lds[buf][0];
        #pragma unroll
        for (int rep = 0; rep < 2; ++rep)
            #pragma unroll
            for (int kk = 0; kk < 2; ++kk) {
                __builtin_amdgcn_global_load_lds(
                    (const __attribute__((address_space(1))) uint32_t*)(const void*)
                        (srcA[rep] + kt * 64 + kk * 32),
                    (__attribute__((address_space(3))) uint32_t*)(void*)
                        (base + kk * 8192 + (rep * 512 + t) * 8), 16, 0, 0);
                __builtin_amdgcn_global_load_lds(
                    (const __attribute__((address_space(1))) uint32_t*)(const void*)
                        (srcB[rep] + (size_t)(kt * 2 + kk) * 32768),
                    (__attribute__((address_space(3))) uint32_t*)(void*)
                        (base + 16384 + kk * 8192 + (rep * 512 + t) * 8), 16, 0, 0);
            }
    };

    auto compute = [&](int buf) {
        const short* L = &lds[buf][0];
        #pragma unroll
        for (int kk = 0; kk < 2; ++kk) {
            bf16x8 bfr[4], af[8];
            #pragma unroll
            for (int g = 0; g < 4; ++g)
                bfr[g] = *(const bf16x8*)&L[bbase + kk * 8192 + g * 2048];
            #pragma unroll
            for (int m = 0; m < 8; ++m)
                af[m] = *(const bf16x8*)&L[abase + kk * 8192 + m * 512];
            __builtin_amdgcn_s_setprio(1);
            #pragma unroll
            for (int g = 0; g < 4; ++g)
                #pragma unroll
                for (int m = 0; m < 8; ++m)
                    acc[m][g] = __builtin_amdgcn_mfma_f32_16x16x32_bf16(af[m], bfr[g], acc[m][g], 0, 0, 0);
            __builtin_amdgcn_s_setprio(0);
        }
    };

    // ---- K loop: 8 phases of BK=64, double-buffered, 1-ahead DMA ----
    dma(0, 0);
    #pragma unroll 1
    for (int kt = 0; kt < 8; ++kt) {
        asm volatile("s_waitcnt vmcnt(0)" ::: "memory");   // own DMA(kt) done
        __builtin_amdgcn_s_barrier();                      // all waves' DMA done
        if (kt < 7) dma(kt + 1, (kt + 1) & 1);             // ~full phase in flight
        compute(kt & 1);
    }

    // ---- fused LSTM epilogue (lane-local: all 4 gates in acc[m][0..3]) ----
    const size_t HS = (size_t)NROWS * NUNITS;
    const int u = ut * 64 + q * 16 + lr;
    const float bi = bias[u],       bfg = bias[256 + u];
    const float bc = bias[512 + u], bo  = bias[768 + u];
    const float ppi = pi[u], ppf = pf[u], ppo = po[u];
    #pragma unroll
    for (int m = 0; m < 8; ++m) {
        #pragma unroll
        for (int r = 0; r < 4; ++r) {
            const int row = row0 + rh * 128 + m * 16 + hi * 4 + r;
            const size_t o = (size_t)row * NUNITS + u;
            const float cp = c_prev[o];
            float zi = acc[m][0][r] + bi  + ppi * cp;
            float zf = acc[m][1][r] + bfg + ppf * cp;
            float zc = acc[m][2][r] + bc;
            float zo = acc[m][3][r] + bo  + ppo * cp;
            float ig = 1.f / (1.f + __expf(-zi));
            float fg = 1.f / (1.f + __expf(-zf));
            float og = 1.f / (1.f + __expf(-zo));
            zc = fminf(fmaxf(zc, -30.f), 30.f);
            float e2 = __expf(2.f * zc);
            float chat = (e2 - 1.f) / (e2 + 1.f);
            float c  = fg * cp + ig * chat;
            float ccl = fminf(fmaxf(c, -30.f), 30.f);
            float e3 = __expf(2.f * ccl);
            float th = (e3 - 1.f) / (e3 + 1.f);
            float h  = og * th;
            out[o]          = h;
            out[HS + o]     = h;
            out[2 * HS + o] = c;
        }
    }
}

extern "C" void kernel_launch(void* const* d_in, const int* in_sizes, int n_in,
                              void* d_out, int out_size, void* d_ws, size_t ws_size,
                              hipStream_t stream) {
    const float* x  = (const float*)d_in[0];
    const float* h  = (const float*)d_in[1];
    const float* c  = (const float*)d_in[2];
    const float* W  = (const float*)d_in[3];
    const float* b  = (const float*)d_in[4];
    const float* pi = (const float*)d_in[5];
    const float* pf = (const float*)d_in[6];
    const float* po = (const float*)d_in[7];
    float* out = (float*)d_out;

    const size_t aws_bytes = (size_t)NROWS * KTOT * 2;   // 134,217,728
    short* Aws = (short*)d_ws;
    short* Wws = (short*)((char*)d_ws + aws_bytes);

    hipLaunchKernelGGL(convert_kernel, dim3(32768 + 2048), dim3(256), 0, stream,
                       x, h, W, Aws, Wws);
    hipLaunchKernelGGL(lstm_main_kernel, dim3(NROWS / BM * 4), dim3(THREADS), 0, stream,
                       c, b, pi, pf, po, Aws, Wws, out);
}

// Round 9
// 322.220 us; speedup vs baseline: 1.0888x; 1.0888x over previous
//
#include <hip/hip_runtime.h>
#include <cstdint>

// Problem constants
#define NROWS   131072
#define NUNITS  256
#define KTOT    512          // INPUT_DIM + UNITS
#define BM      128          // rows per block
#define THREADS 512

typedef float f32x4  __attribute__((ext_vector_type(4)));
typedef short bf16x8 __attribute__((ext_vector_type(8)));

__device__ __forceinline__ short f2bf(float x) {
    unsigned u = __float_as_uint(x);
    u += 0x7FFFu + ((u >> 16) & 1u);   // round-to-nearest-even
    return (short)(u >> 16);
}

// W [512][1024] fp32 -> Wws [16][1024][32] bf16 (B-fragment order, L2-resident).
// Tiny (1 MB out); A is NOT pre-converted anymore (staged fp32 in main).
__global__ void convert_W_kernel(const float* __restrict__ W, short* __restrict__ Wws) {
    int i = blockIdx.x * 256 + threadIdx.x;       // 0 .. 524287
    int k = i >> 10;
    int c = i & 1023;
    Wws[((size_t)(k >> 5) << 15) + ((size_t)c << 5) + (k & 31)] = f2bf(W[i]);
}

// Main: grid 4096 = 1024 row-tiles x 4 u-tiles (XCD-swizzled: the 4 u-tiles of
// a row panel land adjacent on one XCD -> x/h panel L2-reused).
// Block: 128 rows x 64 u x 4 gates. 8 waves = 2 row-halves x 4 col-quarters;
// wave tile 64x64, acc[4][4] (all 4 gates lane-local -> fused epilogue).
// A staged as FP32 via global_load_lds (no prepass), 16 KB/step, TRIPLE-buffered
// (DMA 2 phases ahead -> HBM ~900cyc covered); B bf16 16 KB/step double-buffered
// (L2, 1 phase). Counted vmcnt(2) per phase; raw s_barrier; setprio on MFMA.
// Swizzles (rule #21, source-side; LDS dest linear):
//   A: slot s of row r holds granule g = s ^ (r&7)  (8x16B slots per 128B row)
//      frag read slots 2hi^(lr&7), +^1 -> 8 lanes/slot = b128 size-floor, no excess conflict
//   B: slot bg of col cp holds granule bg ^ ((cp>>1)&3)  (R7-proven, 0 conflicts)
__global__ void __launch_bounds__(THREADS, 4)
lstm_main_kernel(const float* __restrict__ x, const float* __restrict__ h_prev,
                 const float* __restrict__ c_prev, const float* __restrict__ bias,
                 const float* __restrict__ pi, const float* __restrict__ pf,
                 const float* __restrict__ po, const short* __restrict__ Wws,
                 float* __restrict__ out) {
    __shared__ float Alds[3][4096];   // 3 x 16 KB (fp32 A tiles)
    __shared__ short Blds[2][8192];   // 2 x 16 KB (bf16 B tiles)

    const int bid = blockIdx.x;
    const int swz = (bid & 7) * 512 + (bid >> 3);
    const int ut  = swz & 3;
    const int rt  = swz >> 2;
    const int row0 = rt * BM;

    const int t    = threadIdx.x;
    const int lane = t & 63;
    const int w    = t >> 6;
    const int lr   = lane & 15;
    const int hi   = lane >> 4;          // k-granule 0..3
    const int rh   = w >> 2;             // row half 0..1
    const int q    = w & 3;              // col quarter 0..3

    // ---- A DMA sources: thread covers granules G = t and t+512 ----
    // G -> row r = G>>3, LDS slot s = G&7, source granule g = s ^ (r&7)
    const float* aX[2]; const float* aH[2];
    #pragma unroll
    for (int rep = 0; rep < 2; ++rep) {
        const int G = rep * 512 + t;
        const int r = G >> 3, s = G & 7, g = s ^ (r & 7);
        aX[rep] = x      + (size_t)(row0 + r) * 256 + g * 4;
        aH[rep] = h_prev + (size_t)(row0 + r) * 256 + g * 4;
    }
    // ---- B DMA sources (R7 scheme) ----
    const short* srcB[2];
    #pragma unroll
    for (int rep = 0; rep < 2; ++rep) {
        const int G = rep * 512 + t;
        const int cp = G >> 2, bg = G & 3;
        const int gate = cp >> 6, u64 = cp & 63;
        srcB[rep] = Wws + (size_t)(gate * 256 + ut * 64 + u64) * 32
                        + ((bg ^ ((cp >> 1) & 3)) * 8);
    }

    // ---- fragment read offsets ----
    const int s0    = (2 * hi) ^ (lr & 7);               // A slot for first b128
    const int bsw   = (hi ^ ((lr >> 1) & 3)) * 8;        // B granule slot (shorts)
    const int boff  = (q * 16 + lr) * 32 + bsw;          // + g*2048 (shorts)

    f32x4 acc[4][4];
    #pragma unroll
    for (int m = 0; m < 4; ++m)
        #pragma unroll
        for (int g = 0; g < 4; ++g)
            acc[m][g] = (f32x4){0.f, 0.f, 0.f, 0.f};

    auto dmaA = [&](int ks, int buf) {
        const int off = (ks & 7) * 32;
        const float* p0 = (ks < 8 ? aX[0] : aH[0]) + off;
        const float* p1 = (ks < 8 ? aX[1] : aH[1]) + off;
        float* dst = &Alds[buf][0];
        __builtin_amdgcn_global_load_lds(
            (const __attribute__((address_space(1))) uint32_t*)(const void*)p0,
            (__attribute__((address_space(3))) uint32_t*)(void*)(dst + t * 4), 16, 0, 0);
        __builtin_amdgcn_global_load_lds(
            (const __attribute__((address_space(1))) uint32_t*)(const void*)p1,
            (__attribute__((address_space(3))) uint32_t*)(void*)(dst + 2048 + t * 4), 16, 0, 0);
    };
    auto dmaB = [&](int ks, int buf) {
        short* dst = &Blds[buf][0];
        __builtin_amdgcn_global_load_lds(
            (const __attribute__((address_space(1))) uint32_t*)(const void*)(srcB[0] + (size_t)ks * 32768),
            (__attribute__((address_space(3))) uint32_t*)(void*)(dst + t * 8), 16, 0, 0);
        __builtin_amdgcn_global_load_lds(
            (const __attribute__((address_space(1))) uint32_t*)(const void*)(srcB[1] + (size_t)ks * 32768),
            (__attribute__((address_space(3))) uint32_t*)(void*)(dst + 4096 + t * 8), 16, 0, 0);
    };

    auto compute = [&](int abuf, int bbuf) {
        const float* A = &Alds[abuf][0];
        const short* B = &Blds[bbuf][0];
        bf16x8 af[4], bfr[4];
        #pragma unroll
        for (int m = 0; m < 4; ++m) {
            const int r = rh * 64 + m * 16 + lr;
            f32x4 lo = *(const f32x4*)&A[r * 32 + s0 * 4];
            f32x4 hi4 = *(const f32x4*)&A[r * 32 + (s0 ^ 1) * 4];
            unsigned u0, u1, u2, u3;
            asm("v_cvt_pk_bf16_f32 %0, %1, %2" : "=v"(u0) : "v"(lo[0]),  "v"(lo[1]));
            asm("v_cvt_pk_bf16_f32 %0, %1, %2" : "=v"(u1) : "v"(lo[2]),  "v"(lo[3]));
            asm("v_cvt_pk_bf16_f32 %0, %1, %2" : "=v"(u2) : "v"(hi4[0]), "v"(hi4[1]));
            asm("v_cvt_pk_bf16_f32 %0, %1, %2" : "=v"(u3) : "v"(hi4[2]), "v"(hi4[3]));
            unsigned uu[4] = {u0, u1, u2, u3};
            af[m] = *(bf16x8*)uu;
        }
        #pragma unroll
        for (int g = 0; g < 4; ++g)
            bfr[g] = *(const bf16x8*)&B[boff + g * 2048];
        __builtin_amdgcn_s_setprio(1);
        #pragma unroll
        for (int g = 0; g < 4; ++g)
            #pragma unroll
            for (int m = 0; m < 4; ++m)
                acc[m][g] = __builtin_amdgcn_mfma_f32_16x16x32_bf16(af[m], bfr[g], acc[m][g], 0, 0, 0);
        __builtin_amdgcn_s_setprio(0);
    };

    // ---- prologue: A(0), B(0), A(1) in flight ----
    dmaA(0, 0);
    dmaB(0, 0);
    dmaA(1, 1);

    int ab = 0;
    #pragma unroll 1
    for (int p = 0; p < 16; ++p) {
        // retire A(p), B(p); leave A(p+1) (2 instrs) in flight
        if (p < 15) { asm volatile("s_waitcnt vmcnt(2)" ::: "memory"); }
        else        { asm volatile("s_waitcnt vmcnt(0)" ::: "memory"); }
        __builtin_amdgcn_s_barrier();
        if (p < 15) dmaB(p + 1, (p + 1) & 1);
        if (p < 14) { int nb = ab + 2; if (nb >= 3) nb -= 3; dmaA(p + 2, nb); }
        compute(ab, p & 1);
        if (++ab == 3) ab = 0;
    }

    // ---- fused LSTM epilogue (lane-local: all 4 gates in acc[m][0..3]) ----
    const size_t HS = (size_t)NROWS * NUNITS;
    const int u = ut * 64 + q * 16 + lr;
    const float bi = bias[u],       bfg = bias[256 + u];
    const float bc = bias[512 + u], bo  = bias[768 + u];
    const float ppi = pi[u], ppf = pf[u], ppo = po[u];
    #pragma unroll
    for (int m = 0; m < 4; ++m) {
        #pragma unroll
        for (int r = 0; r < 4; ++r) {
            const int row = row0 + rh * 64 + m * 16 + hi * 4 + r;
            const size_t o = (size_t)row * NUNITS + u;
            const float cp = c_prev[o];
            float zi = acc[m][0][r] + bi  + ppi * cp;
            float zf = acc[m][1][r] + bfg + ppf * cp;
            float zc = acc[m][2][r] + bc;
            float zo = acc[m][3][r] + bo  + ppo * cp;
            float ig = 1.f / (1.f + __expf(-zi));
            float fg = 1.f / (1.f + __expf(-zf));
            float og = 1.f / (1.f + __expf(-zo));
            zc = fminf(fmaxf(zc, -30.f), 30.f);
            float e2 = __expf(2.f * zc);
            float chat = (e2 - 1.f) / (e2 + 1.f);
            float c  = fg * cp + ig * chat;
            float ccl = fminf(fmaxf(c, -30.f), 30.f);
            float e3 = __expf(2.f * ccl);
            float th = (e3 - 1.f) / (e3 + 1.f);
            float h  = og * th;
            out[o]          = h;
            out[HS + o]     = h;
            out[2 * HS + o] = c;
        }
    }
}

extern "C" void kernel_launch(void* const* d_in, const int* in_sizes, int n_in,
                              void* d_out, int out_size, void* d_ws, size_t ws_size,
                              hipStream_t stream) {
    const float* x  = (const float*)d_in[0];
    const float* h  = (const float*)d_in[1];
    const float* c  = (const float*)d_in[2];
    const float* W  = (const float*)d_in[3];
    const float* b  = (const float*)d_in[4];
    const float* pi = (const float*)d_in[5];
    const float* pf = (const float*)d_in[6];
    const float* po = (const float*)d_in[7];
    float* out = (float*)d_out;

    short* Wws = (short*)d_ws;            // 1 MiB bf16 copy of W in B-frag order

    hipLaunchKernelGGL(convert_W_kernel, dim3(2048), dim3(256), 0, stream, W, Wws);
    hipLaunchKernelGGL(lstm_main_kernel, dim3(NROWS / BM * 4), dim3(THREADS), 0, stream,
                       x, h, c, b, pi, pf, po, Wws, out);
}